// Round 3
// baseline (42.460 us; speedup 1.0000x reference)
//
#include <hip/hip_runtime.h>
#include <hip/hip_bf16.h>
#include <math.h>

#define NB 8
#define NL 128
#define D_ATOM 256
#define DH 32        // d_hid
#define DAB 64       // 2*d_hid
#define K1 21
#define K2 30
#define KT 51        // K1+K2
#define KP 52        // padded K stride
#define TROW (DH*KP) // 1664 floats per T row
#define ROWS (NB*NL) // 1024
#define LN_EPS 1e-5f

// ---------------- Kernel 1: LN ----------------
// 4 rows per block; W_in staged in LDS (64KB) shared by the 4 waves.
__global__ __launch_bounds__(256) void ln_kernel(
    const float* __restrict__ z, const float* __restrict__ W_in,
    const float* __restrict__ b_in, const float* __restrict__ ln_g,
    const float* __restrict__ ln_b, float* __restrict__ a_out,
    float* __restrict__ b_out)
{
    __shared__ float Wl[D_ATOM * DAB];   // 64 KB
    __shared__ float zl[4][D_ATOM];      // 4 KB
    const int t = threadIdx.x;
    const int w = t >> 6, j = t & 63;
    const int row0 = blockIdx.x * 4;

    #pragma unroll
    for (int s = 0; s < 16; ++s) {
        int i4 = t + s * 256;
        ((float4*)Wl)[i4] = ((const float4*)W_in)[i4];
    }
    ((float4*)zl)[t] = ((const float4*)(z + (size_t)row0 * D_ATOM))[t];
    __syncthreads();

    float acc = b_in[j];
    #pragma unroll 8
    for (int i = 0; i < D_ATOM; ++i)
        acc = fmaf(zl[w][i], Wl[i * DAB + j], acc);

    float g = 0.5f * acc * (1.0f + erff(acc * 0.70710678118654752f));

    float s = g, sq = g * g;
    #pragma unroll
    for (int msk = 1; msk < 64; msk <<= 1) {
        s  += __shfl_xor(s,  msk, 64);
        sq += __shfl_xor(sq, msk, 64);
    }
    float mu  = s  * (1.0f / 64.0f);
    float var = sq * (1.0f / 64.0f) - mu * mu;
    float y = (g - mu) * rsqrtf(var + LN_EPS) * ln_g[j] + ln_b[j];

    const int row = row0 + w;
    if (j < DH) a_out[row * DH + j]        = y;
    else        b_out[row * DH + (j - DH)] = y;
}

// ---------------- Kernel 2: T-GEMM ----------------
// T[row][d*52+k] = sum_c a[row][c] * Wcat[c][d][k]
// block = (row-block of 128) x (one d). grid = 8*32 = 256.
__global__ __launch_bounds__(256) void t_gemm_kernel(
    const float* __restrict__ a_g, const float* __restrict__ W1,
    const float* __restrict__ W2, float* __restrict__ T_all)
{
    const int rb = blockIdx.x >> 5;   // 0..7
    const int d  = blockIdx.x & 31;
    const int t  = threadIdx.x;

    __shared__ float Al[128 * 33];    // [r][c], stride 33 (conflict-free)
    __shared__ float Wl[DH * KP];     // [c][k], stride 52

    #pragma unroll
    for (int s = 0; s < 4; ++s) {
        int i4 = t + s * 256;
        float4 v = ((const float4*)(a_g + (size_t)rb * 128 * DH))[i4];
        int e = i4 * 4, r = e >> 5, c0 = e & 31;
        Al[r * 33 + c0 + 0] = v.x; Al[r * 33 + c0 + 1] = v.y;
        Al[r * 33 + c0 + 2] = v.z; Al[r * 33 + c0 + 3] = v.w;
    }
    #pragma unroll
    for (int s = 0; s < 7; ++s) {
        int idx = t + s * 256;
        if (idx < DH * KT) {
            int c = idx / KT, k = idx % KT;
            float wv = (k < K1) ? W1[(c * DH + d) * K1 + k]
                                : W2[(c * DH + d) * K2 + (k - K1)];
            Wl[c * KP + k] = wv;
        }
    }
    __syncthreads();

    const int r = t & 127, half = t >> 7;
    float av[DH];
    #pragma unroll
    for (int c = 0; c < DH; ++c) av[c] = Al[r * 33 + c];

    const int row = rb * 128 + r;
    float* dst = T_all + (size_t)row * TROW + d * KP;

    if (half == 0) {            // k 0..23
        float acc[24];
        #pragma unroll
        for (int q = 0; q < 24; ++q) acc[q] = 0.f;
        #pragma unroll 4
        for (int c = 0; c < DH; ++c) {
            float a = av[c];
            const float* base = Wl + c * KP;
            #pragma unroll
            for (int q = 0; q < 6; ++q) {
                float4 wv = *(const float4*)&base[q * 4];
                acc[q*4+0] = fmaf(a, wv.x, acc[q*4+0]);
                acc[q*4+1] = fmaf(a, wv.y, acc[q*4+1]);
                acc[q*4+2] = fmaf(a, wv.z, acc[q*4+2]);
                acc[q*4+3] = fmaf(a, wv.w, acc[q*4+3]);
            }
        }
        #pragma unroll
        for (int q = 0; q < 6; ++q) {
            float4 v = { acc[q*4+0], acc[q*4+1], acc[q*4+2], acc[q*4+3] };
            *(float4*)&dst[q * 4] = v;
        }
    } else {                    // k 24..50
        float acc[28];
        #pragma unroll
        for (int q = 0; q < 28; ++q) acc[q] = 0.f;
        #pragma unroll 4
        for (int c = 0; c < DH; ++c) {
            float a = av[c];
            const float* base = Wl + c * KP + 24;
            #pragma unroll
            for (int q = 0; q < 7; ++q) {
                float4 wv = *(const float4*)&base[q * 4];
                acc[q*4+0] = fmaf(a, wv.x, acc[q*4+0]);
                acc[q*4+1] = fmaf(a, wv.y, acc[q*4+1]);
                acc[q*4+2] = fmaf(a, wv.z, acc[q*4+2]);
                acc[q*4+3] = fmaf(a, wv.w, acc[q*4+3]);
            }
        }
        #pragma unroll
        for (int q = 0; q < 6; ++q) {
            float4 v = { acc[q*4+0], acc[q*4+1], acc[q*4+2], acc[q*4+3] };
            *(float4*)&dst[24 + q * 4] = v;
        }
        dst[48] = acc[24]; dst[49] = acc[25]; dst[50] = acc[26];
    }
}

// ---------------- Kernel 3: pair product ----------------
// out[row][m][k] = sum_d bb[batch][m][d] * T[row][d][k] + bias[k]
// 1 row per block, 1024 blocks. thread: m = t&127, half = t>>7.
__global__ __launch_bounds__(256) void pair_kernel(
    const float* __restrict__ b_g, const float* __restrict__ T_all,
    const float* __restrict__ b1v, const float* __restrict__ b2v,
    float* __restrict__ out)
{
    const int row   = blockIdx.x;
    const int batch = row >> 7;
    const int t     = threadIdx.x;

    __shared__ float bbl[NL * 33];    // [m][d], stride 33
    __shared__ float Tl[TROW];        // [d*52+k]

    #pragma unroll
    for (int s = 0; s < 4; ++s) {
        int i4 = t + s * 256;
        float4 v = ((const float4*)(b_g + (size_t)batch * NL * DH))[i4];
        int e = i4 * 4, m = e >> 5, d0 = e & 31;
        bbl[m * 33 + d0 + 0] = v.x; bbl[m * 33 + d0 + 1] = v.y;
        bbl[m * 33 + d0 + 2] = v.z; bbl[m * 33 + d0 + 3] = v.w;
    }
    #pragma unroll
    for (int s = 0; s < 2; ++s) {
        int i4 = t + s * 256;
        if (i4 < TROW / 4)
            ((float4*)Tl)[i4] = ((const float4*)(T_all + (size_t)row * TROW))[i4];
    }
    __syncthreads();

    const int m = t & 127, half = t >> 7;
    float bv[DH];
    #pragma unroll
    for (int d = 0; d < DH; ++d) bv[d] = bbl[m * 33 + d];

    float* o1 = out + (size_t)row * NL * K1 + m * K1;
    float* o2 = out + (size_t)ROWS * NL * K1 + (size_t)row * NL * K2 + m * K2;

    if (half == 0) {            // k 0..23
        float acc[24];
        #pragma unroll
        for (int q = 0; q < 24; ++q) acc[q] = 0.f;
        #pragma unroll 4
        for (int d = 0; d < DH; ++d) {
            float b = bv[d];
            const float* base = Tl + d * KP;
            #pragma unroll
            for (int q = 0; q < 6; ++q) {
                float4 tv = *(const float4*)&base[q * 4];
                acc[q*4+0] = fmaf(b, tv.x, acc[q*4+0]);
                acc[q*4+1] = fmaf(b, tv.y, acc[q*4+1]);
                acc[q*4+2] = fmaf(b, tv.z, acc[q*4+2]);
                acc[q*4+3] = fmaf(b, tv.w, acc[q*4+3]);
            }
        }
        #pragma unroll
        for (int k = 0; k < K1; ++k) o1[k] = acc[k] + b1v[k];
        #pragma unroll
        for (int k = K1; k < 24; ++k) o2[k - K1] = acc[k] + b2v[k - K1];
    } else {                    // k 24..50 (acc[27] = pad, unused)
        float acc[28];
        #pragma unroll
        for (int q = 0; q < 28; ++q) acc[q] = 0.f;
        #pragma unroll 4
        for (int d = 0; d < DH; ++d) {
            float b = bv[d];
            const float* base = Tl + d * KP + 24;
            #pragma unroll
            for (int q = 0; q < 7; ++q) {
                float4 tv = *(const float4*)&base[q * 4];
                acc[q*4+0] = fmaf(b, tv.x, acc[q*4+0]);
                acc[q*4+1] = fmaf(b, tv.y, acc[q*4+1]);
                acc[q*4+2] = fmaf(b, tv.z, acc[q*4+2]);
                acc[q*4+3] = fmaf(b, tv.w, acc[q*4+3]);
            }
        }
        #pragma unroll
        for (int jj = 0; jj < 27; ++jj) {
            int k2 = 3 + jj;            // out2 index = (24+jj)-21
            o2[k2] = acc[jj] + b2v[k2];
        }
    }
}

extern "C" void kernel_launch(void* const* d_in, const int* in_sizes, int n_in,
                              void* d_out, int out_size, void* d_ws, size_t ws_size,
                              hipStream_t stream) {
    const float* z    = (const float*)d_in[0];
    const float* W_in = (const float*)d_in[1];
    const float* b_in = (const float*)d_in[2];
    const float* ln_g = (const float*)d_in[3];
    const float* ln_b = (const float*)d_in[4];
    const float* W1   = (const float*)d_in[5];
    const float* b1   = (const float*)d_in[6];
    const float* W2   = (const float*)d_in[7];
    const float* b2   = (const float*)d_in[8];
    float* out = (float*)d_out;

    float* a_ws  = (float*)d_ws;             // ROWS*DH
    float* b_ws  = a_ws + ROWS * DH;         // ROWS*DH
    float* T_all = b_ws + ROWS * DH;         // ROWS*TROW (6.8 MB)

    ln_kernel<<<ROWS / 4, 256, 0, stream>>>(z, W_in, b_in, ln_g, ln_b, a_ws, b_ws);
    t_gemm_kernel<<<256, 256, 0, stream>>>(a_ws, W1, W2, T_all);
    pair_kernel<<<ROWS, 256, 0, stream>>>(b_ws, T_all, b1, b2, out);
}

// Round 4
// 30.219 us; speedup vs baseline: 1.4051x; 1.4051x over previous
//
#include <hip/hip_runtime.h>
#include <hip/hip_bf16.h>
#include <math.h>

#define NB 8
#define NL 128
#define D_ATOM 256
#define DH 32       // d_hid
#define DAB 64      // 2*d_hid
#define K1 21
#define K2 30
#define KT 51       // K1+K2
#define ROWS (NB*NL) // 1024
#define LN_EPS 1e-5f

#define BBT_STRIDE (NL + 8)   // 136 floats
#define T_STRIDE 52           // padded K
#define OUT1_ROW (NL*K1)      // 2688 floats
#define OUT2_ROW (NL*K2)      // 3840 floats
#define STAGE_N  (OUT1_ROW + OUT2_ROW) // 6528 floats = 25.5 KB

// ---------------- Kernel 1: LN ----------------
// 4 rows per block; W_in staged in LDS (64KB) shared by the 4 waves.
__global__ __launch_bounds__(256) void ln_kernel(
    const float* __restrict__ z, const float* __restrict__ W_in,
    const float* __restrict__ b_in, const float* __restrict__ ln_g,
    const float* __restrict__ ln_b, float* __restrict__ a_out,
    float* __restrict__ b_out)
{
    __shared__ float Wl[D_ATOM * DAB];   // 64 KB
    __shared__ float zl[4][D_ATOM];      // 4 KB
    const int t = threadIdx.x;
    const int w = t >> 6, j = t & 63;
    const int row0 = blockIdx.x * 4;

    #pragma unroll
    for (int s = 0; s < 16; ++s) {
        int i4 = t + s * 256;
        ((float4*)Wl)[i4] = ((const float4*)W_in)[i4];
    }
    ((float4*)zl)[t] = ((const float4*)(z + (size_t)row0 * D_ATOM))[t];
    __syncthreads();

    float acc = b_in[j];
    #pragma unroll 8
    for (int i = 0; i < D_ATOM; ++i)
        acc = fmaf(zl[w][i], Wl[i * DAB + j], acc);

    float g = 0.5f * acc * (1.0f + erff(acc * 0.70710678118654752f));

    float s = g, sq = g * g;
    #pragma unroll
    for (int msk = 1; msk < 64; msk <<= 1) {
        s  += __shfl_xor(s,  msk, 64);
        sq += __shfl_xor(sq, msk, 64);
    }
    float mu  = s  * (1.0f / 64.0f);
    float var = sq * (1.0f / 64.0f) - mu * mu;
    float y = (g - mu) * rsqrtf(var + LN_EPS) * ln_g[j] + ln_b[j];

    const int row = row0 + w;
    if (j < DH) a_out[row * DH + j]        = y;
    else        b_out[row * DH + (j - DH)] = y;
}

// ---------------- Kernel 2: pair product ----------------
// 2 rows (same batch) per block, 256 threads.
// Phase 1: T_r[d][k] = sum_c a[r][c] * Wr[c,d,k]  (inline, coalesced W reads)
// Phase 2: acc[r][i][jj] = sum_d bbT[d][m] * T_r[d][k]   (8m x 4k x 2r per thread)
// Phase 3: stage each row's output in LDS, then fully-coalesced float4 stores.
__global__ __launch_bounds__(256) void pair_proj_kernel(
    const float* __restrict__ a_g, const float* __restrict__ b_g,
    const float* __restrict__ W1, const float* __restrict__ b1v,
    const float* __restrict__ W2, const float* __restrict__ b2v,
    float* __restrict__ out)
{
    const int row0  = blockIdx.x * 2;
    const int batch = row0 >> 7;
    const int t     = threadIdx.x;

    __shared__ float a_lds[2][DH];
    __shared__ float bbT[DH][BBT_STRIDE];        // [d][m] transposed, 17.4 KB
    __shared__ float T_lds[2][DH * T_STRIDE];    // 13.3 KB
    __shared__ __align__(16) float stage[STAGE_N]; // 25.5 KB: [out1 row | out2 row]

    // --- stage a rows + transposed bb ---
    if (t < 2 * DH) a_lds[t >> 5][t & 31] = a_g[row0 * DH + t];
    #pragma unroll
    for (int s = 0; s < 16; ++s) {
        int idx = t + s * 256;                  // idx = m*32 + d
        int m = idx >> 5, d = idx & 31;
        bbT[d][m] = b_g[batch * NL * DH + idx];
    }
    __syncthreads();

    // --- phase 1: inline T compute, coalesced W reads ---
    float tacc0[7], tacc1[7];
    const float* wptr[7];
    int wstr[7], tidx[7];
    bool val[7];
    #pragma unroll
    for (int s = 0; s < 7; ++s) {
        int o = t + s * 256;
        val[s] = (o < 1632);
        int oo = val[s] ? o : 0;
        if (oo < 672) {
            wptr[s] = W1 + oo; wstr[s] = 672;
            int d = oo / 21, k = oo % 21;
            tidx[s] = d * T_STRIDE + k;
        } else {
            int o2 = oo - 672;
            wptr[s] = W2 + o2; wstr[s] = 960;
            int d = o2 / 30, k = 21 + o2 % 30;
            tidx[s] = d * T_STRIDE + k;
        }
        tacc0[s] = 0.f; tacc1[s] = 0.f;
    }
    #pragma unroll 4
    for (int c = 0; c < DH; ++c) {
        float ac0 = a_lds[0][c], ac1 = a_lds[1][c];
        #pragma unroll
        for (int s = 0; s < 7; ++s) {
            float w = wptr[s][c * wstr[s]];
            tacc0[s] = fmaf(ac0, w, tacc0[s]);
            tacc1[s] = fmaf(ac1, w, tacc1[s]);
        }
    }
    #pragma unroll
    for (int s = 0; s < 7; ++s) {
        if (val[s]) { T_lds[0][tidx[s]] = tacc0[s]; T_lds[1][tidx[s]] = tacc1[s]; }
    }
    if (t < DH) { T_lds[0][t * T_STRIDE + 51] = 0.f; T_lds[1][t * T_STRIDE + 51] = 0.f; }
    __syncthreads();

    // --- phase 2: register-tiled pair product ---
    const int mt = t / 13, kt = t % 13;
    const int m0 = mt * 8, k0 = kt * 4;
    const bool active = (t < 208);

    float acc[2][8][4];
    #pragma unroll
    for (int r = 0; r < 2; ++r)
        #pragma unroll
        for (int i = 0; i < 8; ++i)
            #pragma unroll
            for (int jj = 0; jj < 4; ++jj) acc[r][i][jj] = 0.f;

    if (active) {
        #pragma unroll 4
        for (int d = 0; d < DH; ++d) {
            float4 bv0 = *(const float4*)&bbT[d][m0];
            float4 bv1 = *(const float4*)&bbT[d][m0 + 4];
            float4 t0  = *(const float4*)&T_lds[0][d * T_STRIDE + k0];
            float4 t1  = *(const float4*)&T_lds[1][d * T_STRIDE + k0];
            float bv[8] = {bv0.x, bv0.y, bv0.z, bv0.w, bv1.x, bv1.y, bv1.z, bv1.w};
            float tv0[4] = {t0.x, t0.y, t0.z, t0.w};
            float tv1[4] = {t1.x, t1.y, t1.z, t1.w};
            #pragma unroll
            for (int i = 0; i < 8; ++i) {
                #pragma unroll
                for (int jj = 0; jj < 4; ++jj) {
                    acc[0][i][jj] = fmaf(bv[i], tv0[jj], acc[0][i][jj]);
                    acc[1][i][jj] = fmaf(bv[i], tv1[jj], acc[1][i][jj]);
                }
            }
        }
    }

    float bias[4];
    #pragma unroll
    for (int jj = 0; jj < 4; ++jj) {
        int k = k0 + jj;
        bias[jj] = (k < K1) ? b1v[k] : (k < KT ? b2v[k - K1] : 0.f);
    }

    // --- phase 3: per-row LDS staging + coalesced stores ---
    const float* b2base = b2v; (void)b2base;
    #pragma unroll
    for (int r = 0; r < 2; ++r) {
        if (r == 1) __syncthreads();   // row0 copy-out done before overwrite
        if (active) {
            #pragma unroll
            for (int i = 0; i < 8; ++i) {
                const int m = m0 + i;
                #pragma unroll
                for (int jj = 0; jj < 4; ++jj) {
                    const int k = k0 + jj;
                    float v = acc[r][i][jj] + bias[jj];
                    if (k < K1)      stage[m * K1 + k] = v;
                    else if (k < KT) stage[OUT1_ROW + m * K2 + (k - K1)] = v;
                }
            }
        }
        __syncthreads();

        const int row = row0 + r;
        float* o1 = out + (size_t)row * OUT1_ROW;
        float* o2 = out + (size_t)ROWS * OUT1_ROW + (size_t)row * OUT2_ROW;
        const float4* s1 = (const float4*)stage;
        const float4* s2 = (const float4*)(stage + OUT1_ROW);
        for (int i4 = t; i4 < OUT1_ROW / 4; i4 += 256)
            ((float4*)o1)[i4] = s1[i4];
        for (int i4 = t; i4 < OUT2_ROW / 4; i4 += 256)
            ((float4*)o2)[i4] = s2[i4];
    }
}

extern "C" void kernel_launch(void* const* d_in, const int* in_sizes, int n_in,
                              void* d_out, int out_size, void* d_ws, size_t ws_size,
                              hipStream_t stream) {
    const float* z    = (const float*)d_in[0];
    const float* W_in = (const float*)d_in[1];
    const float* b_in = (const float*)d_in[2];
    const float* ln_g = (const float*)d_in[3];
    const float* ln_b = (const float*)d_in[4];
    const float* W1   = (const float*)d_in[5];
    const float* b1   = (const float*)d_in[6];
    const float* W2   = (const float*)d_in[7];
    const float* b2   = (const float*)d_in[8];
    float* out = (float*)d_out;

    float* a_ws = (float*)d_ws;            // ROWS*DH floats
    float* b_ws = a_ws + ROWS * DH;        // ROWS*DH floats (total 256 KB)

    ln_kernel<<<ROWS / 4, 256, 0, stream>>>(z, W_in, b_in, ln_g, ln_b, a_ws, b_ws);
    pair_proj_kernel<<<ROWS / 2, 256, 0, stream>>>(a_ws, b_ws, W1, b1, W2, b2, out);
}

// Round 5
// 23.945 us; speedup vs baseline: 1.7733x; 1.2620x over previous
//
#include <hip/hip_runtime.h>
#include <hip/hip_bf16.h>
#include <math.h>

#define NB 8
#define NL 128
#define D_ATOM 256
#define DH 32       // d_hid
#define DAB 64      // 2*d_hid
#define K1 21
#define K2 30
#define KT 51       // K1+K2
#define ROWS (NB*NL) // 1024
#define LN_EPS 1e-5f

#define OUT1_ROW (NL*K1)      // 2688 floats
#define OUT2_ROW (NL*K2)      // 3840 floats
#define STAGE_N  (OUT1_ROW + OUT2_ROW) // 6528 floats

typedef __attribute__((ext_vector_type(8))) short bf16x8;
typedef __attribute__((ext_vector_type(4))) float f32x4;

__device__ __forceinline__ unsigned short f2bf(float x) {
    __hip_bfloat16 h = __float2bfloat16(x);
    return *reinterpret_cast<unsigned short*>(&h);
}

// ---------------- Kernel 1: LN ----------------
__global__ __launch_bounds__(256) void ln_kernel(
    const float* __restrict__ z, const float* __restrict__ W_in,
    const float* __restrict__ b_in, const float* __restrict__ ln_g,
    const float* __restrict__ ln_b, float* __restrict__ a_out,
    float* __restrict__ b_out)
{
    __shared__ float Wl[D_ATOM * DAB];   // 64 KB
    __shared__ float zl[4][D_ATOM];      // 4 KB
    const int t = threadIdx.x;
    const int w = t >> 6, j = t & 63;
    const int row0 = blockIdx.x * 4;

    #pragma unroll
    for (int s = 0; s < 16; ++s) {
        int i4 = t + s * 256;
        ((float4*)Wl)[i4] = ((const float4*)W_in)[i4];
    }
    ((float4*)zl)[t] = ((const float4*)(z + (size_t)row0 * D_ATOM))[t];
    __syncthreads();

    float acc = b_in[j];
    #pragma unroll 8
    for (int i = 0; i < D_ATOM; ++i)
        acc = fmaf(zl[w][i], Wl[i * DAB + j], acc);

    float g = 0.5f * acc * (1.0f + erff(acc * 0.70710678118654752f));

    float s = g, sq = g * g;
    #pragma unroll
    for (int msk = 1; msk < 64; msk <<= 1) {
        s  += __shfl_xor(s,  msk, 64);
        sq += __shfl_xor(sq, msk, 64);
    }
    float mu  = s  * (1.0f / 64.0f);
    float var = sq * (1.0f / 64.0f) - mu * mu;
    float y = (g - mu) * rsqrtf(var + LN_EPS) * ln_g[j] + ln_b[j];

    const int row = row0 + w;
    if (j < DH) a_out[row * DH + j]        = y;
    else        b_out[row * DH + (j - DH)] = y;
}

// ---------------- Kernel 2: pair product (MFMA) ----------------
// 2 rows per block. Phase 1 (VALU): T_r[d][k] = sum_c a[r][c]*W[c,d,k], written
// bf16 fragment-ordered. Phase 2: out[r][m][k] via mfma_f32_16x16x32_bf16
// (A = bb 16x32, B = T 32x16, K=32 in one shot). Phase 3: LDS stage + coalesced.
__global__ __launch_bounds__(256) void pair_mfma_kernel(
    const float* __restrict__ a_g, const float* __restrict__ b_g,
    const float* __restrict__ W1, const float* __restrict__ b1v,
    const float* __restrict__ W2, const float* __restrict__ b2v,
    float* __restrict__ out)
{
    const int row0  = blockIdx.x * 2;
    const int batch = row0 >> 7;
    const int t     = threadIdx.x;

    // A-fragments: bbf[mt][lane][8] bf16  (m = mt*16 + (lane&15), d = 8*(lane>>4)+j)
    __shared__ unsigned short bbf[8 * 64 * 8];       // 8 KB
    // B-fragments: Tf[r][kt][lane][8] bf16 (k = kt*16 + (lane&15), d = 8*(lane>>4)+j)
    __shared__ unsigned short Tf[2 * 4 * 64 * 8];    // 8 KB
    __shared__ float a_lds[2][DH];
    __shared__ __align__(16) float stg[2][STAGE_N];  // 51 KB

    // --- staging: a rows, zero Tf, bb -> A-fragment order (bf16) ---
    if (t < 2 * DH) a_lds[t >> 5][t & 31] = a_g[row0 * DH + t];

    #pragma unroll
    for (int s = 0; s < 8; ++s)
        ((unsigned int*)Tf)[t + s * 256] = 0u;

    #pragma unroll
    for (int s = 0; s < 2; ++s) {
        int e = t + s * 256;                 // fragment entry 0..511
        int mt = e >> 6, l = e & 63;
        int m = mt * 16 + (l & 15), d0 = (l >> 4) * 8;
        const float4* p = (const float4*)(b_g + ((size_t)batch * NL + m) * DH + d0);
        float4 v0 = p[0], v1 = p[1];
        uint4 wv;
        wv.x = (unsigned)f2bf(v0.x) | ((unsigned)f2bf(v0.y) << 16);
        wv.y = (unsigned)f2bf(v0.z) | ((unsigned)f2bf(v0.w) << 16);
        wv.z = (unsigned)f2bf(v1.x) | ((unsigned)f2bf(v1.y) << 16);
        wv.w = (unsigned)f2bf(v1.z) | ((unsigned)f2bf(v1.w) << 16);
        ((uint4*)bbf)[e] = wv;
    }
    __syncthreads();

    // --- phase 1: T = a @ W (VALU, coalesced W reads), write bf16 fragments ---
    float tacc0[7], tacc1[7];
    const float* wptr[7];
    int wstr[7], fidx[7];
    bool val[7];
    #pragma unroll
    for (int s = 0; s < 7; ++s) {
        int o = t + s * 256;
        val[s] = (o < 1632);
        int oo = val[s] ? o : 0;
        int d, k;
        if (oo < 672) {
            wptr[s] = W1 + oo; wstr[s] = 672;
            d = oo / 21; k = oo % 21;
        } else {
            int o2 = oo - 672;
            wptr[s] = W2 + o2; wstr[s] = 960;
            d = o2 / 30; k = 21 + o2 % 30;
        }
        int kt = k >> 4, lane = (k & 15) | ((d >> 3) << 4), reg = d & 7;
        fidx[s] = (kt * 64 + lane) * 8 + reg;
        tacc0[s] = 0.f; tacc1[s] = 0.f;
    }
    #pragma unroll 4
    for (int c = 0; c < DH; ++c) {
        float ac0 = a_lds[0][c], ac1 = a_lds[1][c];
        #pragma unroll
        for (int s = 0; s < 7; ++s) {
            float w = wptr[s][c * wstr[s]];
            tacc0[s] = fmaf(ac0, w, tacc0[s]);
            tacc1[s] = fmaf(ac1, w, tacc1[s]);
        }
    }
    #pragma unroll
    for (int s = 0; s < 7; ++s) {
        if (val[s]) {
            Tf[fidx[s]]        = f2bf(tacc0[s]);
            Tf[2048 + fidx[s]] = f2bf(tacc1[s]);
        }
    }
    __syncthreads();

    // --- phase 2: MFMA ---
    const int w  = t >> 6, l = t & 63;
    const int r  = w >> 1;            // row within pair
    const int mh = w & 1;             // m-half: m-tiles mh*4 .. mh*4+3

    bf16x8 af[4], bfr[4];
    #pragma unroll
    for (int i = 0; i < 4; ++i)
        af[i] = ((const bf16x8*)bbf)[(mh * 4 + i) * 64 + l];
    #pragma unroll
    for (int kt = 0; kt < 4; ++kt)
        bfr[kt] = ((const bf16x8*)Tf)[(r * 4 + kt) * 64 + l];

    float bias[4];
    #pragma unroll
    for (int kt = 0; kt < 4; ++kt) {
        int k = kt * 16 + (l & 15);
        bias[kt] = (k < K1) ? b1v[k] : (k < KT ? b2v[k - K1] : 0.f);
    }

    #pragma unroll
    for (int i = 0; i < 4; ++i) {
        const int mbase = (mh * 4 + i) * 16 + (l >> 4) * 4;
        #pragma unroll
        for (int kt = 0; kt < 4; ++kt) {
            f32x4 acc = __builtin_amdgcn_mfma_f32_16x16x32_bf16(
                af[i], bfr[kt], (f32x4){0.f, 0.f, 0.f, 0.f}, 0, 0, 0);
            const int k = kt * 16 + (l & 15);
            if (k < K1) {
                #pragma unroll
                for (int q = 0; q < 4; ++q)
                    stg[r][(mbase + q) * K1 + k] = acc[q] + bias[kt];
            } else if (k < KT) {
                #pragma unroll
                for (int q = 0; q < 4; ++q)
                    stg[r][OUT1_ROW + (mbase + q) * K2 + (k - K1)] = acc[q] + bias[kt];
            }
        }
    }
    __syncthreads();

    // --- phase 3: coalesced copy-out of both rows ---
    #pragma unroll
    for (int rr = 0; rr < 2; ++rr) {
        const int row = row0 + rr;
        float* o1 = out + (size_t)row * OUT1_ROW;
        float* o2 = out + (size_t)ROWS * OUT1_ROW + (size_t)row * OUT2_ROW;
        const float4* s1 = (const float4*)stg[rr];
        const float4* s2 = (const float4*)(stg[rr] + OUT1_ROW);
        for (int i4 = t; i4 < OUT1_ROW / 4; i4 += 256)
            ((float4*)o1)[i4] = s1[i4];
        for (int i4 = t; i4 < OUT2_ROW / 4; i4 += 256)
            ((float4*)o2)[i4] = s2[i4];
    }
}

extern "C" void kernel_launch(void* const* d_in, const int* in_sizes, int n_in,
                              void* d_out, int out_size, void* d_ws, size_t ws_size,
                              hipStream_t stream) {
    const float* z    = (const float*)d_in[0];
    const float* W_in = (const float*)d_in[1];
    const float* b_in = (const float*)d_in[2];
    const float* ln_g = (const float*)d_in[3];
    const float* ln_b = (const float*)d_in[4];
    const float* W1   = (const float*)d_in[5];
    const float* b1   = (const float*)d_in[6];
    const float* W2   = (const float*)d_in[7];
    const float* b2   = (const float*)d_in[8];
    float* out = (float*)d_out;

    float* a_ws = (float*)d_ws;            // ROWS*DH floats
    float* b_ws = a_ws + ROWS * DH;        // ROWS*DH floats

    ln_kernel<<<ROWS / 4, 256, 0, stream>>>(z, W_in, b_in, ln_g, ln_b, a_ws, b_ws);
    pair_mfma_kernel<<<ROWS / 2, 256, 0, stream>>>(a_ws, b_ws, W1, b1, W2, b2, out);
}